// Round 10
// baseline (229.456 us; speedup 1.0000x reference)
//
#include <hip/hip_runtime.h>
#include <math.h>

#define BB 16
#define NN 4096
#define DD 128
#define KK 256          // C*P = 4*64
#define NROWS (BB*NN)   // 65536
#define WIN 7
#define HWIN 3
#define ALPHA 0.5f
#define EPS 1e-5f

typedef __attribute__((ext_vector_type(8))) short bf16x8;
typedef __attribute__((ext_vector_type(4))) float f32x4;

__device__ __forceinline__ unsigned short f2b(float f) {     // f32 -> bf16 RNE
    unsigned u = __float_as_uint(f);
    u += 0x7FFFu + ((u >> 16) & 1u);
    return (unsigned short)(u >> 16);
}
__device__ __forceinline__ float b2f_lo(unsigned v) { return __uint_as_float(v << 16); }
__device__ __forceinline__ float b2f_hi(unsigned v) { return __uint_as_float(v & 0xFFFF0000u); }
__device__ __forceinline__ float lrelu(float v) { return v >= 0.f ? v : 0.1f * v; }

__device__ __forceinline__ unsigned cvtpk(float lo, float hi) { // lo->low16, hi->high16
    unsigned r;
    asm("v_cvt_pk_bf16_f32 %0, %1, %2" : "=v"(r) : "v"(lo), "v"(hi));
    return r;
}

__device__ __forceinline__ uint4 pack8(float4 a, float4 b) {
    uint4 v;
    v.x = (unsigned)f2b(a.x)  | ((unsigned)f2b(a.y)  << 16);
    v.y = (unsigned)f2b(a.z)  | ((unsigned)f2b(a.w)  << 16);
    v.z = (unsigned)f2b(b.x)  | ((unsigned)f2b(b.y)  << 16);
    v.w = (unsigned)f2b(b.z)  | ((unsigned)f2b(b.w)  << 16);
    return v;
}

#define GL2LDS(gp, lp) __builtin_amdgcn_global_load_lds( \
    (const __attribute__((address_space(1))) void*)(gp), \
    (__attribute__((address_space(3))) void*)(lp), 16, 0, 0)

// ---------------------------------------------------------------------------
// Kernel P: W f32 [128][256] -> bf16 FRAGMENT-MAJOR image.  (round-5 verbatim)
// ---------------------------------------------------------------------------
__global__ __launch_bounds__(256) void k_prep(
    const float* __restrict__ W, uint4* __restrict__ Wfrag)
{
    const int id   = blockIdx.x * 256 + threadIdx.x;   // 0..4095
    const int lane = id & 63, f = id >> 6;
    const int k = f & 7, w = f >> 3;
    const int d = w * 16 + (lane & 15);
    const int c = k * 32 + (lane >> 4) * 8;
    const float4 a = *(const float4*)(&W[(size_t)d * KK + c]);
    const float4 b = *(const float4*)(&W[(size_t)d * KK + c + 4]);
    Wfrag[id] = pack8(a, b);
}

// ---------------------------------------------------------------------------
// Kernel A: h = bf16mfma(X @ W^T) + b (h bf16) + per-feature sum/sumsq.
// ROUND-5 VERBATIM (known-good, 58 us): gl2lds staging, swizzled via permuted
// global source + XOR'd read, dbuf 2x32 KB, __syncthreads per subtile.
// ---------------------------------------------------------------------------
__global__ __launch_bounds__(512, 4) void k_embed(
    const float* __restrict__ x,
    const float* __restrict__ xt,
    const uint4* __restrict__ Wfrag,
    const float* __restrict__ bvec,
    unsigned short* __restrict__ h_out,   // [2][NROWS][DD] bf16
    float* __restrict__ sums)             // [2][2][DD]
{
    __shared__ float Xs[2][32 * 256];     // 2 x 32 KB f32

    const int blk  = blockIdx.x;          // 512
    const int src  = blk >> 8;
    const int tile = blk & 255;
    const int row0 = tile * 256;
    const float* __restrict__ X = src ? xt : x;
    unsigned short* __restrict__ H = h_out + (size_t)src * NROWS * DD;

    const int t    = threadIdx.x;
    const int lane = t & 63;
    const int w    = t >> 6;              // 0..7 : cols w*16..+16
    const int l15  = lane & 15;
    const int lg   = lane >> 4;           // 0..3

    // W fragments -> registers (L2/L3-resident after first block)
    bf16x8 breg[8];
    #pragma unroll
    for (int k = 0; k < 8; ++k) {
        uint4 u = Wfrag[(w * 8 + k) * 64 + lane];
        breg[k] = *(bf16x8*)&u;
    }

    const float bv = bvec[w * 16 + l15];
    float s = 0.f, q = 0.f;

    // stage one 32-row subtile: wave w stages rows 4w..4w+3 (4 x 1KB instrs)
    #define STAGE(sub, b)                                                     \
    {                                                                         \
        const float* base_ = X + (size_t)(row0 + (sub) * 32) * KK;            \
        _Pragma("unroll")                                                     \
        for (int j_ = 0; j_ < 4; ++j_) {                                      \
            const int i_ = w * 4 + j_;                                        \
            const float* gp_ = base_ + i_ * KK + ((lane ^ (i_ & 15)) << 2);   \
            GL2LDS(gp_, &Xs[b][i_ * 256]);                                    \
        }                                                                     \
    }

    STAGE(0, 0);
    __syncthreads();

    #pragma unroll 1
    for (int st = 0; st < 8; ++st) {
        if (st < 7) STAGE(st + 1, (st + 1) & 1);

        const float* xb = &Xs[st & 1][0];
        f32x4 acc[2];
        #pragma unroll
        for (int m = 0; m < 2; ++m)
            #pragma unroll
            for (int j = 0; j < 4; ++j) acc[m][j] = 0.f;

        #pragma unroll
        for (int k = 0; k < 8; ++k) {
            const int u0 = k * 8 + lg * 2;        // 16B-unit of the k-slice
            #pragma unroll
            for (int m = 0; m < 2; ++m) {
                const float* pr = xb + (m * 16 + l15) * 256;
                const f32x4 a0 = *(const f32x4*)(pr + ((u0 ^ l15) << 2));
                const f32x4 a1 = *(const f32x4*)(pr + (((u0 + 1) ^ l15) << 2));
                uint4 uu;
                uu.x = cvtpk(a0[0], a0[1]);
                uu.y = cvtpk(a0[2], a0[3]);
                uu.z = cvtpk(a1[0], a1[1]);
                uu.w = cvtpk(a1[2], a1[3]);
                const bf16x8 av = *(const bf16x8*)&uu;
                acc[m] = __builtin_amdgcn_mfma_f32_16x16x32_bf16(av, breg[k], acc[m], 0, 0, 0);
            }
        }

        // epilogue: bias, bf16 store, sums.  C/D: col=lane&15, row=lg*4+j
        #pragma unroll
        for (int m = 0; m < 2; ++m) {
            #pragma unroll
            for (int j = 0; j < 4; ++j) {
                const int row = row0 + st * 32 + m * 16 + lg * 4 + j;
                const float v = acc[m][j] + bv;
                H[(size_t)row * DD + w * 16 + l15] = f2b(v);
                s += v; q += v * v;
            }
        }
        __syncthreads();
    }
    #undef STAGE

    // per-col reduce: wave w exclusively owns cols w*16..+16
    s += __shfl_xor(s, 16); s += __shfl_xor(s, 32);
    q += __shfl_xor(q, 16); q += __shfl_xor(q, 32);
    if (lane < 16) {
        atomicAdd(&sums[src * 256 + w * 16 + l15], s);
        atomicAdd(&sums[src * 256 + 128 + w * 16 + l15], q);
    }
}

// ---------------------------------------------------------------------------
// Kernel S: stats finalize + normalize + leaky + windowed sim + masked
// softmax.  Writes feat (raw sim) and attn weights [B][N][8] to workspace.
// (= validated phases 0-2 + softmax of the old k_attn, minus the blend.)
// ---------------------------------------------------------------------------
__global__ __launch_bounds__(256) void k_sim(
    const unsigned short* __restrict__ h,   // [2][NROWS][DD] bf16
    const float* __restrict__ sums,         // [2][2][DD]
    const float* __restrict__ gamma,
    const float* __restrict__ beta,
    float* __restrict__ attn_ws,            // [B*N*8]
    float* __restrict__ feat)               // [B*N*7]
{
    const int blk  = blockIdx.x;
    const int bb   = blk >> 7;
    const int tile = blk & 127;
    const int n0   = tile * 32;
    const int t    = threadIdx.x;

    __shared__ float ex[32][132];
    __shared__ float et[38][132];
    __shared__ float attnw[32][8];
    __shared__ float ssl[512];              // [2][2][DD] scale/shift

    const unsigned short* __restrict__ Hx = h;
    const unsigned short* __restrict__ Ht = h + (size_t)NROWS * DD;
    const size_t rowbase = (size_t)bb * NN;

    // phase 0: recompute scale/shift from global sums
    {
        const int s_ = t >> 7, d = t & 127;
        const float invn = 1.0f / (float)NROWS;
        const float mean = sums[s_ * 256 + d] * invn;
        const float var  = sums[s_ * 256 + 128 + d] * invn - mean * mean;
        const float sc   = gamma[d] / sqrtf(var + EPS);
        ssl[s_ * 256 + d]       = sc;
        ssl[s_ * 256 + 128 + d] = beta[d] - mean * sc;
    }
    __syncthreads();

    // phase 1: emb_x / emb_t -> LDS f32 (normalize + leaky on the fly)
    #pragma unroll
    for (int p = 0; p < 2; ++p) {
        const int j = t + p * 256;
        const int r = j >> 4, c8 = j & 15;
        const uint4 u = *(const uint4*)(&Hx[(rowbase + n0 + r) * DD + c8 * 8]);
        const float4 sca = *(const float4*)(&ssl[c8 * 8]);
        const float4 scb = *(const float4*)(&ssl[c8 * 8 + 4]);
        const float4 sha = *(const float4*)(&ssl[128 + c8 * 8]);
        const float4 shb = *(const float4*)(&ssl[128 + c8 * 8 + 4]);
        float* dst = &ex[r][c8 * 8];
        dst[0] = lrelu(b2f_lo(u.x) * sca.x + sha.x);
        dst[1] = lrelu(b2f_hi(u.x) * sca.y + sha.y);
        dst[2] = lrelu(b2f_lo(u.y) * sca.z + sha.z);
        dst[3] = lrelu(b2f_hi(u.y) * sca.w + sha.w);
        dst[4] = lrelu(b2f_lo(u.z) * scb.x + shb.x);
        dst[5] = lrelu(b2f_hi(u.z) * scb.y + shb.y);
        dst[6] = lrelu(b2f_lo(u.w) * scb.z + shb.z);
        dst[7] = lrelu(b2f_hi(u.w) * scb.w + shb.w);
    }
    #pragma unroll
    for (int p = 0; p < 3; ++p) {
        const int j = t + p * 256;
        if (j < 608) {
            const int r = j >> 4, c8 = j & 15;
            int g = n0 - HWIN + r;
            g = min(max(g, 0), NN - 1);
            const uint4 u = *(const uint4*)(&Ht[(rowbase + g) * DD + c8 * 8]);
            const float4 sca = *(const float4*)(&ssl[256 + c8 * 8]);
            const float4 scb = *(const float4*)(&ssl[256 + c8 * 8 + 4]);
            const float4 sha = *(const float4*)(&ssl[384 + c8 * 8]);
            const float4 shb = *(const float4*)(&ssl[384 + c8 * 8 + 4]);
            float* dst = &et[r][c8 * 8];
            dst[0] = lrelu(b2f_lo(u.x) * sca.x + sha.x);
            dst[1] = lrelu(b2f_hi(u.x) * sca.y + sha.y);
            dst[2] = lrelu(b2f_lo(u.y) * sca.z + sha.z);
            dst[3] = lrelu(b2f_hi(u.y) * sca.w + sha.w);
            dst[4] = lrelu(b2f_lo(u.z) * scb.x + shb.x);
            dst[5] = lrelu(b2f_hi(u.z) * scb.y + shb.y);
            dst[6] = lrelu(b2f_lo(u.w) * scb.z + shb.z);
            dst[7] = lrelu(b2f_hi(u.w) * scb.w + shb.w);
        }
    }
    __syncthreads();

    // phase 2: sim (224 threads: 32 n x 7 w dots of length 128)
    if (t < 224) {
        const int n_i = t / 7;
        const int wv  = t % 7;
        const float* a = &ex[n_i][0];
        const float* b = &et[n_i + wv][0];
        float acc = 0.f;
        #pragma unroll
        for (int d4 = 0; d4 < 128; d4 += 4) {
            const float4 av = *(const float4*)(a + d4);
            const float4 bv = *(const float4*)(b + d4);
            acc += av.x * bv.x + av.y * bv.y + av.z * bv.z + av.w * bv.w;
        }
        feat[(rowbase + n0 + n_i) * WIN + wv] = acc;
        attnw[n_i][wv] = acc;
    }
    __syncthreads();

    // phase 3: masked softmax (32 threads, one n each)
    if (t < 32) {
        const int n = n0 + t;
        float mx = -1e30f;
        #pragma unroll
        for (int wv = 0; wv < WIN; ++wv) {
            const int c = n + wv - HWIN;
            if (c >= 0 && c < NN) mx = fmaxf(mx, attnw[t][wv]);
        }
        float e[WIN];
        float esum = 0.f;
        #pragma unroll
        for (int wv = 0; wv < WIN; ++wv) {
            const int c = n + wv - HWIN;
            const bool valid = (c >= 0 && c < NN);
            e[wv] = valid ? expf(attnw[t][wv] - mx) : 0.f;
            esum += e[wv];
        }
        const float inv = 1.0f / esum;
        #pragma unroll
        for (int wv = 0; wv < WIN; ++wv) attnw[t][wv] = e[wv] * inv;
        attnw[t][7] = 0.f;
    }
    __syncthreads();

    // phase 4: store attn tile (32 n x 8, one float per thread, coalesced)
    attn_ws[(size_t)blk * 256 + t] = attnw[t >> 3][t & 7];
}

// ---------------------------------------------------------------------------
// Kernel O: streaming blend  out = alpha*x + (1-alpha)*sum_w attn[w]*xt[win].
// Per wave-iteration all 64 lanes read one contiguous 1 KB row (perfectly
// coalesced); xt window rows come from L1/L2 (7x reuse inside the block).
// XCD-aware swizzle keeps neighboring tiles (shared xt rows) on one L2.
// ---------------------------------------------------------------------------
__global__ __launch_bounds__(256) void k_out(
    const float* __restrict__ x,
    const float* __restrict__ xt,
    const float* __restrict__ attn_ws,      // [B*N*8]
    float* __restrict__ out)                // [B*N*KK]
{
    // bijective XCD swizzle: 2048 % 8 == 0
    const int braw = blockIdx.x;
    const int blk  = (braw & 7) * 256 + (braw >> 3);
    const int bb   = blk >> 7;
    const int tile = blk & 127;
    const int n0   = tile * 32;
    const int t    = threadIdx.x;

    __shared__ float als[256];              // attn tile [32][8]
    als[t] = attn_ws[(size_t)blk * 256 + t];
    __syncthreads();

    const size_t rowbase = (size_t)bb * NN;
    #pragma unroll
    for (int p = 0; p < 8; ++p) {
        const int idx = t + p * 256;        // 2048 float4 = 32 rows x 64
        const int n_i = idx >> 6, e4 = idx & 63;
        const int n = n0 + n_i;
        const float4 xv = *(const float4*)(&x[(rowbase + n) * KK + e4 * 4]);
        float4 acc = make_float4(0.f, 0.f, 0.f, 0.f);
        #pragma unroll
        for (int wv = 0; wv < WIN; ++wv) {
            int g = n + wv - HWIN;
            g = min(max(g, 0), NN - 1);
            const float aw = als[n_i * 8 + wv];
            const float4 tv = *(const float4*)(&xt[(rowbase + g) * KK + e4 * 4]);
            acc.x += aw * tv.x;
            acc.y += aw * tv.y;
            acc.z += aw * tv.z;
            acc.w += aw * tv.w;
        }
        float4 o;
        o.x = ALPHA * xv.x + (1.f - ALPHA) * acc.x;
        o.y = ALPHA * xv.y + (1.f - ALPHA) * acc.y;
        o.z = ALPHA * xv.z + (1.f - ALPHA) * acc.z;
        o.w = ALPHA * xv.w + (1.f - ALPHA) * acc.w;
        *(float4*)(&out[(rowbase + n) * KK + e4 * 4]) = o;
    }
}

// ---------------------------------------------------------------------------
extern "C" void kernel_launch(void* const* d_in, const int* in_sizes, int n_in,
                              void* d_out, int out_size, void* d_ws, size_t ws_size,
                              hipStream_t stream) {
    const float* x     = (const float*)d_in[0];
    const float* xt    = (const float*)d_in[1];
    const float* W     = (const float*)d_in[2];
    const float* bvec  = (const float*)d_in[3];
    const float* gamma = (const float*)d_in[4];
    const float* beta  = (const float*)d_in[5];

    float* out  = (float*)d_out;
    float* feat = out + (size_t)BB * NN * KK;

    char* ws = (char*)d_ws;
    unsigned short* h  = (unsigned short*)ws;                  // 32 MiB
    float* sums        = (float*)(ws + 33554432);              // 2 KiB
    unsigned char* Wfr = (unsigned char*)(ws + 33556480);      // 64 KiB
    float* attn        = (float*)(ws + 33622016);              // 2 MiB

    hipMemsetAsync(sums, 0, 512 * sizeof(float), stream);
    k_prep<<<16, 256, 0, stream>>>(W, (uint4*)Wfr);
    k_embed<<<512, 512, 0, stream>>>(x, xt, (const uint4*)Wfr, bvec, h, sums);
    k_sim<<<2048, 256, 0, stream>>>(h, sums, gamma, beta, attn, feat);
    k_out<<<2048, 256, 0, stream>>>(x, xt, attn, out);
}

// Round 11
// 221.458 us; speedup vs baseline: 1.0361x; 1.0361x over previous
//
#include <hip/hip_runtime.h>
#include <math.h>

#define BB 16
#define NN 4096
#define DD 128
#define KK 256          // C*P = 4*64
#define NROWS (BB*NN)   // 65536
#define WIN 7
#define HWIN 3
#define ALPHA 0.5f
#define EPS 1e-5f

typedef __attribute__((ext_vector_type(8))) short bf16x8;
typedef __attribute__((ext_vector_type(4))) float f32x4;

__device__ __forceinline__ unsigned short f2b(float f) {     // f32 -> bf16 RNE
    unsigned u = __float_as_uint(f);
    u += 0x7FFFu + ((u >> 16) & 1u);
    return (unsigned short)(u >> 16);
}
__device__ __forceinline__ float b2f_lo(unsigned v) { return __uint_as_float(v << 16); }
__device__ __forceinline__ float b2f_hi(unsigned v) { return __uint_as_float(v & 0xFFFF0000u); }
__device__ __forceinline__ float lrelu(float v) { return v >= 0.f ? v : 0.1f * v; }

__device__ __forceinline__ unsigned cvtpk(float lo, float hi) { // lo->low16, hi->high16
    unsigned r;
    asm("v_cvt_pk_bf16_f32 %0, %1, %2" : "=v"(r) : "v"(lo), "v"(hi));
    return r;
}

__device__ __forceinline__ uint4 pack8(float4 a, float4 b) {
    uint4 v;
    v.x = (unsigned)f2b(a.x)  | ((unsigned)f2b(a.y)  << 16);
    v.y = (unsigned)f2b(a.z)  | ((unsigned)f2b(a.w)  << 16);
    v.z = (unsigned)f2b(b.x)  | ((unsigned)f2b(b.y)  << 16);
    v.w = (unsigned)f2b(b.z)  | ((unsigned)f2b(b.w)  << 16);
    return v;
}

#define GL2LDS(gp, lp) __builtin_amdgcn_global_load_lds( \
    (const __attribute__((address_space(1))) void*)(gp), \
    (__attribute__((address_space(3))) void*)(lp), 16, 0, 0)

// ---------------------------------------------------------------------------
// Kernel P: W f32 [128][256] -> bf16 FRAGMENT-MAJOR image.  (round-5 verbatim)
// ---------------------------------------------------------------------------
__global__ __launch_bounds__(256) void k_prep(
    const float* __restrict__ W, uint4* __restrict__ Wfrag)
{
    const int id   = blockIdx.x * 256 + threadIdx.x;   // 0..4095
    const int lane = id & 63, f = id >> 6;
    const int k = f & 7, w = f >> 3;
    const int d = w * 16 + (lane & 15);
    const int c = k * 32 + (lane >> 4) * 8;
    const float4 a = *(const float4*)(&W[(size_t)d * KK + c]);
    const float4 b = *(const float4*)(&W[(size_t)d * KK + c + 4]);
    Wfrag[id] = pack8(a, b);
}

// ---------------------------------------------------------------------------
// Kernel A: h = bf16mfma(X @ W^T) + b (h bf16) + per-feature sum/sumsq.
// ROUND-5 VERBATIM (known-good, 58 us).
// ---------------------------------------------------------------------------
__global__ __launch_bounds__(512, 4) void k_embed(
    const float* __restrict__ x,
    const float* __restrict__ xt,
    const uint4* __restrict__ Wfrag,
    const float* __restrict__ bvec,
    unsigned short* __restrict__ h_out,   // [2][NROWS][DD] bf16
    float* __restrict__ sums)             // [2][2][DD]
{
    __shared__ float Xs[2][32 * 256];     // 2 x 32 KB f32

    const int blk  = blockIdx.x;          // 512
    const int src  = blk >> 8;
    const int tile = blk & 255;
    const int row0 = tile * 256;
    const float* __restrict__ X = src ? xt : x;
    unsigned short* __restrict__ H = h_out + (size_t)src * NROWS * DD;

    const int t    = threadIdx.x;
    const int lane = t & 63;
    const int w    = t >> 6;              // 0..7 : cols w*16..+16
    const int l15  = lane & 15;
    const int lg   = lane >> 4;           // 0..3

    // W fragments -> registers (L2/L3-resident after first block)
    bf16x8 breg[8];
    #pragma unroll
    for (int k = 0; k < 8; ++k) {
        uint4 u = Wfrag[(w * 8 + k) * 64 + lane];
        breg[k] = *(bf16x8*)&u;
    }

    const float bv = bvec[w * 16 + l15];
    float s = 0.f, q = 0.f;

    // stage one 32-row subtile: wave w stages rows 4w..4w+3 (4 x 1KB instrs)
    #define STAGE(sub, b)                                                     \
    {                                                                         \
        const float* base_ = X + (size_t)(row0 + (sub) * 32) * KK;            \
        _Pragma("unroll")                                                     \
        for (int j_ = 0; j_ < 4; ++j_) {                                      \
            const int i_ = w * 4 + j_;                                        \
            const float* gp_ = base_ + i_ * KK + ((lane ^ (i_ & 15)) << 2);   \
            GL2LDS(gp_, &Xs[b][i_ * 256]);                                    \
        }                                                                     \
    }

    STAGE(0, 0);
    __syncthreads();

    #pragma unroll 1
    for (int st = 0; st < 8; ++st) {
        if (st < 7) STAGE(st + 1, (st + 1) & 1);

        const float* xb = &Xs[st & 1][0];
        f32x4 acc[2];
        #pragma unroll
        for (int m = 0; m < 2; ++m)
            #pragma unroll
            for (int j = 0; j < 4; ++j) acc[m][j] = 0.f;

        #pragma unroll
        for (int k = 0; k < 8; ++k) {
            const int u0 = k * 8 + lg * 2;        // 16B-unit of the k-slice
            #pragma unroll
            for (int m = 0; m < 2; ++m) {
                const float* pr = xb + (m * 16 + l15) * 256;
                const f32x4 a0 = *(const f32x4*)(pr + ((u0 ^ l15) << 2));
                const f32x4 a1 = *(const f32x4*)(pr + (((u0 + 1) ^ l15) << 2));
                uint4 uu;
                uu.x = cvtpk(a0[0], a0[1]);
                uu.y = cvtpk(a0[2], a0[3]);
                uu.z = cvtpk(a1[0], a1[1]);
                uu.w = cvtpk(a1[2], a1[3]);
                const bf16x8 av = *(const bf16x8*)&uu;
                acc[m] = __builtin_amdgcn_mfma_f32_16x16x32_bf16(av, breg[k], acc[m], 0, 0, 0);
            }
        }

        // epilogue: bias, bf16 store, sums.  C/D: col=lane&15, row=lg*4+j
        #pragma unroll
        for (int m = 0; m < 2; ++m) {
            #pragma unroll
            for (int j = 0; j < 4; ++j) {
                const int row = row0 + st * 32 + m * 16 + lg * 4 + j;
                const float v = acc[m][j] + bv;
                H[(size_t)row * DD + w * 16 + l15] = f2b(v);
                s += v; q += v * v;
            }
        }
        __syncthreads();
    }
    #undef STAGE

    // per-col reduce: wave w exclusively owns cols w*16..+16
    s += __shfl_xor(s, 16); s += __shfl_xor(s, 32);
    q += __shfl_xor(q, 16); q += __shfl_xor(q, 32);
    if (lane < 16) {
        atomicAdd(&sums[src * 256 + w * 16 + l15], s);
        atomicAdd(&sums[src * 256 + 128 + w * 16 + l15], q);
    }
}

// ---------------------------------------------------------------------------
// Kernel C: MONOLITHIC attn = round-5 phases 0-2 (ssl / normalize / sim)
// + 32-thread masked softmax + ROUND-1-STYLE direct-xt blend (no xt LDS
// staging, xt window rows served by L1/L2 with 7x in-block reuse).
// ---------------------------------------------------------------------------
__global__ __launch_bounds__(256) void k_attn(
    const float* __restrict__ x,
    const float* __restrict__ xt,
    const unsigned short* __restrict__ h,   // [2][NROWS][DD] bf16
    const float* __restrict__ sums,         // [2][2][DD]
    const float* __restrict__ gamma,
    const float* __restrict__ beta,
    float* __restrict__ out,
    float* __restrict__ feat)
{
    const int blk  = blockIdx.x;
    const int bb   = blk >> 7;
    const int tile = blk & 127;
    const int n0   = tile * 32;
    const int t    = threadIdx.x;

    __shared__ float ex[32][132];
    __shared__ float et[38][132];
    __shared__ float attnw[32][8];
    __shared__ float ssl[512];              // [2][2][DD] scale/shift

    const unsigned short* __restrict__ Hx = h;
    const unsigned short* __restrict__ Ht = h + (size_t)NROWS * DD;
    const size_t rowbase = (size_t)bb * NN;

    // phase 0: recompute scale/shift from global sums
    {
        const int s_ = t >> 7, d = t & 127;
        const float invn = 1.0f / (float)NROWS;
        const float mean = sums[s_ * 256 + d] * invn;
        const float var  = sums[s_ * 256 + 128 + d] * invn - mean * mean;
        const float sc   = gamma[d] / sqrtf(var + EPS);
        ssl[s_ * 256 + d]       = sc;
        ssl[s_ * 256 + 128 + d] = beta[d] - mean * sc;
    }
    __syncthreads();

    // phase 1: emb_x / emb_t -> LDS f32 (normalize + leaky on the fly)
    #pragma unroll
    for (int p = 0; p < 2; ++p) {
        const int j = t + p * 256;
        const int r = j >> 4, c8 = j & 15;
        const uint4 u = *(const uint4*)(&Hx[(rowbase + n0 + r) * DD + c8 * 8]);
        const float4 sca = *(const float4*)(&ssl[c8 * 8]);
        const float4 scb = *(const float4*)(&ssl[c8 * 8 + 4]);
        const float4 sha = *(const float4*)(&ssl[128 + c8 * 8]);
        const float4 shb = *(const float4*)(&ssl[128 + c8 * 8 + 4]);
        float* dst = &ex[r][c8 * 8];
        dst[0] = lrelu(b2f_lo(u.x) * sca.x + sha.x);
        dst[1] = lrelu(b2f_hi(u.x) * sca.y + sha.y);
        dst[2] = lrelu(b2f_lo(u.y) * sca.z + sha.z);
        dst[3] = lrelu(b2f_hi(u.y) * sca.w + sha.w);
        dst[4] = lrelu(b2f_lo(u.z) * scb.x + shb.x);
        dst[5] = lrelu(b2f_hi(u.z) * scb.y + shb.y);
        dst[6] = lrelu(b2f_lo(u.w) * scb.z + shb.z);
        dst[7] = lrelu(b2f_hi(u.w) * scb.w + shb.w);
    }
    #pragma unroll
    for (int p = 0; p < 3; ++p) {
        const int j = t + p * 256;
        if (j < 608) {
            const int r = j >> 4, c8 = j & 15;
            int g = n0 - HWIN + r;
            g = min(max(g, 0), NN - 1);
            const uint4 u = *(const uint4*)(&Ht[(rowbase + g) * DD + c8 * 8]);
            const float4 sca = *(const float4*)(&ssl[256 + c8 * 8]);
            const float4 scb = *(const float4*)(&ssl[256 + c8 * 8 + 4]);
            const float4 sha = *(const float4*)(&ssl[384 + c8 * 8]);
            const float4 shb = *(const float4*)(&ssl[384 + c8 * 8 + 4]);
            float* dst = &et[r][c8 * 8];
            dst[0] = lrelu(b2f_lo(u.x) * sca.x + sha.x);
            dst[1] = lrelu(b2f_hi(u.x) * sca.y + sha.y);
            dst[2] = lrelu(b2f_lo(u.y) * sca.z + sha.z);
            dst[3] = lrelu(b2f_hi(u.y) * sca.w + sha.w);
            dst[4] = lrelu(b2f_lo(u.z) * scb.x + shb.x);
            dst[5] = lrelu(b2f_hi(u.z) * scb.y + shb.y);
            dst[6] = lrelu(b2f_lo(u.w) * scb.z + shb.z);
            dst[7] = lrelu(b2f_hi(u.w) * scb.w + shb.w);
        }
    }
    __syncthreads();

    // phase 2: sim (224 threads: 32 n x 7 w dots of length 128)
    if (t < 224) {
        const int n_i = t / 7;
        const int wv  = t % 7;
        const float* a = &ex[n_i][0];
        const float* b = &et[n_i + wv][0];
        float acc = 0.f;
        #pragma unroll
        for (int d4 = 0; d4 < 128; d4 += 4) {
            const float4 av = *(const float4*)(a + d4);
            const float4 bv = *(const float4*)(b + d4);
            acc += av.x * bv.x + av.y * bv.y + av.z * bv.z + av.w * bv.w;
        }
        feat[(rowbase + n0 + n_i) * WIN + wv] = acc;
        attnw[n_i][wv] = acc;
    }
    __syncthreads();

    // phase 3: masked softmax (32 threads, one n each)
    if (t < 32) {
        const int n = n0 + t;
        float mx = -1e30f;
        #pragma unroll
        for (int wv = 0; wv < WIN; ++wv) {
            const int c = n + wv - HWIN;
            if (c >= 0 && c < NN) mx = fmaxf(mx, attnw[t][wv]);
        }
        float e[WIN];
        float esum = 0.f;
        #pragma unroll
        for (int wv = 0; wv < WIN; ++wv) {
            const int c = n + wv - HWIN;
            const bool valid = (c >= 0 && c < NN);
            e[wv] = valid ? expf(attnw[t][wv] - mx) : 0.f;
            esum += e[wv];
        }
        const float inv = 1.0f / esum;
        #pragma unroll
        for (int wv = 0; wv < WIN; ++wv) attnw[t][wv] = e[wv] * inv;
    }
    __syncthreads();

    // phase 4: blend, direct xt reads (round-1 style: 7x L1/L2 row reuse)
    #pragma unroll
    for (int p = 0; p < 8; ++p) {
        const int idx = t + p * 256;            // 2048 float4 = 32 rows x 64
        const int n_i = idx >> 6, e4 = idx & 63;
        const int n = n0 + n_i;
        const float4 xv = *(const float4*)(&x[(rowbase + n) * KK + e4 * 4]);
        float4 acc = make_float4(0.f, 0.f, 0.f, 0.f);
        #pragma unroll
        for (int wv = 0; wv < WIN; ++wv) {
            int g = n + wv - HWIN;
            g = min(max(g, 0), NN - 1);
            const float aw = attnw[n_i][wv];
            const float4 tv = *(const float4*)(&xt[(rowbase + g) * KK + e4 * 4]);
            acc.x += aw * tv.x;
            acc.y += aw * tv.y;
            acc.z += aw * tv.z;
            acc.w += aw * tv.w;
        }
        float4 o;
        o.x = ALPHA * xv.x + (1.f - ALPHA) * acc.x;
        o.y = ALPHA * xv.y + (1.f - ALPHA) * acc.y;
        o.z = ALPHA * xv.z + (1.f - ALPHA) * acc.z;
        o.w = ALPHA * xv.w + (1.f - ALPHA) * acc.w;
        *(float4*)(&out[(rowbase + n) * KK + e4 * 4]) = o;
    }
}

// ---------------------------------------------------------------------------
extern "C" void kernel_launch(void* const* d_in, const int* in_sizes, int n_in,
                              void* d_out, int out_size, void* d_ws, size_t ws_size,
                              hipStream_t stream) {
    const float* x     = (const float*)d_in[0];
    const float* xt    = (const float*)d_in[1];
    const float* W     = (const float*)d_in[2];
    const float* bvec  = (const float*)d_in[3];
    const float* gamma = (const float*)d_in[4];
    const float* beta  = (const float*)d_in[5];

    float* out  = (float*)d_out;
    float* feat = out + (size_t)BB * NN * KK;

    char* ws = (char*)d_ws;
    unsigned short* h  = (unsigned short*)ws;                  // 32 MiB
    float* sums        = (float*)(ws + 33554432);              // 2 KiB
    unsigned char* Wfr = (unsigned char*)(ws + 33556480);      // 64 KiB

    hipMemsetAsync(sums, 0, 512 * sizeof(float), stream);
    k_prep<<<16, 256, 0, stream>>>(W, (uint4*)Wfr);
    k_embed<<<512, 512, 0, stream>>>(x, xt, (const uint4*)Wfr, bvec, h, sums);
    k_attn<<<2048, 256, 0, stream>>>(x, xt, h, sums, gamma, beta, out, feat);
}